// Round 1
// baseline (1247.659 us; speedup 1.0000x reference)
//
#include <hip/hip_runtime.h>

constexpr int B_ = 2, N_ = 16384, E_ = 131072, C_ = 128, K_ = 64, FC_ = 128, L_ = 4;

__device__ __forceinline__ float gelu_f(float x) {
    return 0.5f * x * (1.0f + erff(x * 0.70710678118654752f));
}

// ---------------- bases: bc_t/bs_t in (B,K,N) layout, mask folded in ----------------
__global__ __launch_bounds__(256) void bases_kernel(const float* __restrict__ nodes,
                                                    const float* __restrict__ modes,
                                                    const float* __restrict__ node_mask,
                                                    float* __restrict__ bc_t,
                                                    float* __restrict__ bs_t) {
    int idx = blockIdx.x * blockDim.x + threadIdx.x;   // (b,k,n), n fastest; total B*K*N = 2^21
    int n = idx & (N_ - 1);
    int k = (idx >> 14) & (K_ - 1);
    int b = idx >> 20;
    float n0 = nodes[(b * N_ + n) * 2 + 0];
    float n1 = nodes[(b * N_ + n) * 2 + 1];
    float t = n0 * modes[k * 2 + 0] + n1 * modes[k * 2 + 1];
    float s, c;
    sincosf(t, &s, &c);
    float m = node_mask[b * N_ + n];
    bc_t[idx] = c * m;
    bs_t[idx] = s * m;
}

// ---------------- fc0: h[b][c][n] = x[b][n][:3] @ fc0_w + b ----------------
__global__ __launch_bounds__(256) void fc0_kernel(const float* __restrict__ x,
                                                  const float* __restrict__ w,
                                                  const float* __restrict__ bias,
                                                  float* __restrict__ h) {
    int idx = blockIdx.x * blockDim.x + threadIdx.x;   // (b,c,n), n fastest; total B*C*N = 2^22
    int n = idx & (N_ - 1);
    int c = (idx >> 14) & (C_ - 1);
    int b = idx >> 21;
    const float* xr = x + (b * N_ + n) * 3;
    h[idx] = fmaf(xr[0], w[0 * C_ + c], fmaf(xr[1], w[1 * C_ + c], fmaf(xr[2], w[2 * C_ + c], bias[c])));
}

// ---------------- x0 moment (f64 accumulate over N) ----------------
__global__ __launch_bounds__(256) void x0_kernel(const float* __restrict__ h,
                                                 const float* __restrict__ mask,
                                                 const float* __restrict__ wt,
                                                 double* __restrict__ x0) {
    int bc = blockIdx.x;           // b*C + c
    int b = bc >> 7;
    int t = threadIdx.x;
    const float* hr = h + (size_t)bc * N_;
    const float* mr = mask + b * N_;
    const float* wr = wt + b * N_;
    double acc = 0.0;
    for (int n = t; n < N_; n += 256)
        acc += (double)hr[n] * (double)(mr[n] * wr[n]);
    __shared__ double red[256];
    red[t] = acc;
    __syncthreads();
    for (int s = 128; s > 0; s >>= 1) { if (t < s) red[t] += red[t + s]; __syncthreads(); }
    if (t == 0) x0[bc] = red[0];
}

// ---------------- spectral moments: xc/xs[b][c][k], f64 atomic accumulate ----------------
// grid (B, C/16, 32); block 256. node_weights folded into h tile here.
__global__ __launch_bounds__(256) void moments_kernel(const float* __restrict__ h,
                                                      const float* __restrict__ wt,
                                                      const float* __restrict__ bc_t,
                                                      const float* __restrict__ bs_t,
                                                      double* __restrict__ xc,
                                                      double* __restrict__ xs) {
    int b = blockIdx.x, c0 = blockIdx.y * 16, nbase = blockIdx.z * (N_ / 32);  // 512-wide n range
    __shared__ float hw[16][64];
    __shared__ float bcl[64][65];
    __shared__ float bsl[64][65];
    int t = threadIdx.x;
    int k = t & 63, cg = t >> 6;   // cg in 0..3 -> 4 c rows each
    double ac[4] = {0, 0, 0, 0}, as[4] = {0, 0, 0, 0};
    for (int nc = 0; nc < 512; nc += 64) {
        int n0 = nbase + nc;
        __syncthreads();
        for (int i = t; i < 16 * 64; i += 256) {
            int ci = i >> 6, nj = i & 63;
            hw[ci][nj] = h[(b * C_ + c0 + ci) * N_ + n0 + nj] * wt[b * N_ + n0 + nj];
        }
        for (int i = t; i < 64 * 64; i += 256) {
            int kk = i >> 6, nj = i & 63;
            bcl[kk][nj] = bc_t[(b * K_ + kk) * N_ + n0 + nj];
            bsl[kk][nj] = bs_t[(b * K_ + kk) * N_ + n0 + nj];
        }
        __syncthreads();
        #pragma unroll 8
        for (int nj = 0; nj < 64; ++nj) {
            float bcv = bcl[k][nj], bsv = bsl[k][nj];
            #pragma unroll
            for (int r = 0; r < 4; ++r) {
                float hv = hw[cg * 4 + r][nj];
                ac[r] += (double)hv * (double)bcv;
                as[r] -= (double)hv * (double)bsv;
            }
        }
    }
    #pragma unroll
    for (int r = 0; r < 4; ++r) {
        atomicAdd(&xc[(b * C_ + c0 + cg * 4 + r) * K_ + k], ac[r]);
        atomicAdd(&xs[(b * C_ + c0 + cg * 4 + r) * K_ + k], as[r]);
    }
}

// ---------------- mode-mix (per-k CxC), small ----------------
__global__ __launch_bounds__(256) void mix_kernel(const double* __restrict__ xc,
                                                  const double* __restrict__ xs,
                                                  const float* __restrict__ wc,
                                                  const float* __restrict__ ws,
                                                  float* __restrict__ fc,
                                                  float* __restrict__ fs) {
    int idx = blockIdx.x * blockDim.x + threadIdx.x;   // (b*C + o)*K + k
    int k = idx & 63, o = (idx >> 6) & 127, b = idx >> 13;
    double afc = 0.0, afs = 0.0;
    for (int i = 0; i < C_; ++i) {
        double xcv = xc[(b * C_ + i) * K_ + k], xsv = xs[(b * C_ + i) * K_ + k];
        double wcv = (double)wc[(i * C_ + o) * K_ + k], wsv = (double)ws[(i * C_ + o) * K_ + k];
        afc += xcv * wcv - xsv * wsv;
        afs += xsv * wcv + xcv * wsv;
    }
    fc[idx] = (float)afc;
    fs[idx] = (float)afs;
}

__global__ __launch_bounds__(256) void mix0_kernel(const double* __restrict__ x0,
                                                   const float* __restrict__ w0,
                                                   float* __restrict__ f0) {
    int idx = threadIdx.x;         // 1 block of 256: (b*C + o)
    int o = idx & 127, b = idx >> 7;
    double a = 0.0;
    for (int i = 0; i < C_; ++i) a += x0[b * C_ + i] * (double)w0[i * C_ + o];
    f0[idx] = (float)a;
}

// ---------------- synthesis + pointwise Conv1d fused: hnew = x1 + x2 ----------------
// grid (B, C/8, N/1024); block 256; each thread 4 n's.
__global__ __launch_bounds__(256) void synth_kernel(const float* __restrict__ h,
                                                    const float* __restrict__ bc_t,
                                                    const float* __restrict__ bs_t,
                                                    const float* __restrict__ mask,
                                                    const float* __restrict__ fc,
                                                    const float* __restrict__ fs,
                                                    const float* __restrict__ f0,
                                                    const float* __restrict__ ww,
                                                    const float* __restrict__ wb,
                                                    float* __restrict__ hnew) {
    int b = blockIdx.x, o0 = blockIdx.y * 8, n0 = blockIdx.z * 1024;
    __shared__ float fc2[8][64], fs2[8][64], wwl[8][128], f0l[8], wbl[8];
    int t = threadIdx.x;
    for (int i = t; i < 8 * 64; i += 256) {
        int oi = i >> 6, kk = i & 63;
        fc2[oi][kk] = 2.0f * fc[(b * C_ + o0 + oi) * K_ + kk];
        fs2[oi][kk] = 2.0f * fs[(b * C_ + o0 + oi) * K_ + kk];
    }
    for (int i = t; i < 8 * 128; i += 256) {
        int oi = i >> 7, ii = i & 127;
        wwl[oi][ii] = ww[(o0 + oi) * C_ + ii];
    }
    if (t < 8) { f0l[t] = f0[b * C_ + o0 + t]; wbl[t] = wb[o0 + t]; }
    __syncthreads();
    int nn[4];
    float mv[4];
    #pragma unroll
    for (int j = 0; j < 4; ++j) { nn[j] = n0 + j * 256 + t; mv[j] = mask[b * N_ + nn[j]]; }
    float acc[8][4];
    #pragma unroll
    for (int oi = 0; oi < 8; ++oi)
        #pragma unroll
        for (int j = 0; j < 4; ++j) acc[oi][j] = f0l[oi] * mv[j] + wbl[oi];
    for (int kk = 0; kk < K_; ++kk) {
        const float* bcr = bc_t + (b * K_ + kk) * N_;
        const float* bsr = bs_t + (b * K_ + kk) * N_;
        float bcv[4], bsv[4];
        #pragma unroll
        for (int j = 0; j < 4; ++j) { bcv[j] = bcr[nn[j]]; bsv[j] = bsr[nn[j]]; }
        #pragma unroll
        for (int oi = 0; oi < 8; ++oi) {
            float fcv = fc2[oi][kk], fsv = fs2[oi][kk];
            #pragma unroll
            for (int j = 0; j < 4; ++j) acc[oi][j] += fcv * bcv[j] - fsv * bsv[j];
        }
    }
    for (int ii = 0; ii < C_; ++ii) {
        const float* hr = h + (b * C_ + ii) * N_;
        float hv[4];
        #pragma unroll
        for (int j = 0; j < 4; ++j) hv[j] = hr[nn[j]];
        #pragma unroll
        for (int oi = 0; oi < 8; ++oi) {
            float wv = wwl[oi][ii];
            #pragma unroll
            for (int j = 0; j < 4; ++j) acc[oi][j] += wv * hv[j];
        }
    }
    #pragma unroll
    for (int oi = 0; oi < 8; ++oi) {
        float* hw = hnew + (b * C_ + o0 + oi) * N_;
        #pragma unroll
        for (int j = 0; j < 4; ++j) hw[nn[j]] = acc[oi][j];
    }
}

// ---------------- generic channel GEMM: out = act(W @ in + b), optional transposed out ----------------
// grid (B, C/16, N/512); block 256; thread handles n = n0 + 2t + {0,1}.
template <bool GELU_ACT, bool TRANSPOSED_OUT, bool W_TRANSPOSED>
__global__ __launch_bounds__(256) void cgemm_kernel(const float* __restrict__ in,
                                                    const float* __restrict__ W,
                                                    const float* __restrict__ bias,
                                                    float* __restrict__ out) {
    int b = blockIdx.x, o0 = blockIdx.y * 16, n0 = blockIdx.z * 512;
    __shared__ float wl[16][128];
    __shared__ float bl[16];
    int t = threadIdx.x;
    for (int i = t; i < 16 * 128; i += 256) {
        int oi = i >> 7, ii = i & 127;
        wl[oi][ii] = W_TRANSPOSED ? W[ii * C_ + (o0 + oi)] : W[(o0 + oi) * C_ + ii];
    }
    if (t < 16) bl[t] = bias[t + o0];
    __syncthreads();
    int n = n0 + t * 2;
    float acc[16][2];
    #pragma unroll
    for (int oi = 0; oi < 16; ++oi) { acc[oi][0] = bl[oi]; acc[oi][1] = bl[oi]; }
    for (int ii = 0; ii < C_; ++ii) {
        float2 v = *(const float2*)(in + (b * C_ + ii) * N_ + n);
        #pragma unroll
        for (int oi = 0; oi < 16; ++oi) {
            float wv = wl[oi][ii];
            acc[oi][0] += wv * v.x;
            acc[oi][1] += wv * v.y;
        }
    }
    if (TRANSPOSED_OUT) {
        #pragma unroll
        for (int j = 0; j < 2; ++j) {
            float* orow = out + (size_t)(b * N_ + n + j) * C_ + o0;
            #pragma unroll
            for (int q = 0; q < 4; ++q) {
                float4 v4;
                v4.x = GELU_ACT ? gelu_f(acc[q * 4 + 0][j]) : acc[q * 4 + 0][j];
                v4.y = GELU_ACT ? gelu_f(acc[q * 4 + 1][j]) : acc[q * 4 + 1][j];
                v4.z = GELU_ACT ? gelu_f(acc[q * 4 + 2][j]) : acc[q * 4 + 2][j];
                v4.w = GELU_ACT ? gelu_f(acc[q * 4 + 3][j]) : acc[q * 4 + 3][j];
                *(float4*)(orow + q * 4) = v4;
            }
        }
    } else {
        #pragma unroll
        for (int oi = 0; oi < 16; ++oi) {
            float2 v2;
            v2.x = GELU_ACT ? gelu_f(acc[oi][0]) : acc[oi][0];
            v2.y = GELU_ACT ? gelu_f(acc[oi][1]) : acc[oi][1];
            *(float2*)(out + (b * C_ + o0 + oi) * N_ + n) = v2;
        }
    }
}

// ---------------- edge gather/kernel/scatter ----------------
// block 256 = 2 edges x 128 channels; grid B*E/2
__global__ __launch_bounds__(256) void scatter_kernel(const int* __restrict__ edges,
                                                      const float* __restrict__ nodes,
                                                      const float* __restrict__ ft,
                                                      const float* __restrict__ isw,
                                                      const float* __restrict__ isb,
                                                      const float* __restrict__ gC,
                                                      int l,
                                                      float* __restrict__ x3t) {
    int t = threadIdx.x;
    int sub = t >> 7, c = t & 127;
    int be = blockIdx.x * 2 + sub;        // b*E + e
    int b = be >> 17;                      // E = 2^17
    const int* er = edges + (size_t)be * 2;
    int s = er[0], tg = er[1];
    float ef0 = nodes[(b * N_ + s) * 2 + 0] - nodes[(b * N_ + tg) * 2 + 0];
    float ef1 = nodes[(b * N_ + s) * 2 + 1] - nodes[(b * N_ + tg) * 2 + 1];
    float sig0 = isw[0] * ef0 + isw[1] * ef1 + isb[0];
    float sig1 = isw[2] * ef0 + isw[3] * ef1 + isb[1];
    float ker = gC[l] * expf(ef0 * sig0 + ef1 * sig1);
    float v = ft[(size_t)(b * N_ + s) * C_ + c] * ker;
    atomicAdd(&x3t[(size_t)(b * N_ + tg) * C_ + c], v);
}

// ---------------- combine: h = gelu(hnew) + gelu(x3t^T) ----------------
// grid (B, C/32, N/64); block 256
__global__ __launch_bounds__(256) void combine_kernel(const float* __restrict__ hnew,
                                                      const float* __restrict__ x3t,
                                                      float* __restrict__ h) {
    int b = blockIdx.x, c0 = blockIdx.y * 32, n0 = blockIdx.z * 64;
    __shared__ float tl[32][65];
    int t = threadIdx.x;
    int ci = t & 31, nj = t >> 5;
    #pragma unroll
    for (int p = 0; p < 8; ++p) {
        int n = n0 + p * 8 + nj;
        tl[ci][p * 8 + nj] = x3t[(size_t)(b * N_ + n) * C_ + c0 + ci];
    }
    __syncthreads();
    int nj2 = t & 63, ci2 = t >> 6;
    #pragma unroll
    for (int p = 0; p < 8; ++p) {
        int c = c0 + p * 4 + ci2;
        int idx = (b * C_ + c) * N_ + n0 + nj2;
        h[idx] = gelu_f(hnew[idx]) + gelu_f(tl[p * 4 + ci2][nj2]);
    }
}

// ---------------- final fc2 contraction ----------------
__global__ __launch_bounds__(256) void f2_kernel(const float* __restrict__ y1,
                                                 const float* __restrict__ w2,
                                                 const float* __restrict__ b2,
                                                 float* __restrict__ out) {
    int idx = blockIdx.x * blockDim.x + threadIdx.x;   // b*N + n
    int n = idx & (N_ - 1), b = idx >> 14;
    float acc = b2[0];
    for (int f = 0; f < FC_; ++f) acc += y1[(b * FC_ + f) * N_ + n] * w2[f];
    out[idx] = acc;
}

extern "C" void kernel_launch(void* const* d_in, const int* in_sizes, int n_in,
                              void* d_out, int out_size, void* d_ws, size_t ws_size,
                              hipStream_t stream) {
    const float* x         = (const float*)d_in[0];
    const float* node_mask = (const float*)d_in[1];
    const float* nodes     = (const float*)d_in[2];
    const float* node_w    = (const float*)d_in[3];
    const int*   edges     = (const int*)d_in[4];
    const float* modes     = (const float*)d_in[5];
    const float* fc0_w     = (const float*)d_in[6];
    const float* fc0_b     = (const float*)d_in[7];
    const float* sp_wc     = (const float*)d_in[8];
    const float* sp_ws     = (const float*)d_in[9];
    const float* sp_w0     = (const float*)d_in[10];
    const float* w_w       = (const float*)d_in[11];
    const float* w_b       = (const float*)d_in[12];
    const float* g_w1      = (const float*)d_in[13];
    const float* g_b1      = (const float*)d_in[14];
    const float* g_w2      = (const float*)d_in[15];
    const float* g_b2      = (const float*)d_in[16];
    const float* isw       = (const float*)d_in[17];
    const float* isb       = (const float*)d_in[18];
    const float* gC        = (const float*)d_in[19];
    const float* fc1_w     = (const float*)d_in[20];
    const float* fc1_b     = (const float*)d_in[21];
    const float* fc2_w     = (const float*)d_in[22];
    const float* fc2_b     = (const float*)d_in[23];
    float* out = (float*)d_out;

    // workspace layout (floats): bc_t 2M | bs_t 2M | h 4M | hnew 4M | mbuf 4M | doubles | small floats
    float* bc_t = (float*)d_ws;
    float* bs_t = bc_t + (size_t)B_ * K_ * N_;
    float* h    = bs_t + (size_t)B_ * K_ * N_;
    float* hnew = h + (size_t)B_ * C_ * N_;
    float* mbuf = hnew + (size_t)B_ * C_ * N_;
    double* xc  = (double*)(mbuf + (size_t)B_ * C_ * N_);   // 64MB offset, 8B aligned
    double* xs  = xc + B_ * C_ * K_;
    double* x0  = xs + B_ * C_ * K_;
    float* fcb  = (float*)(x0 + B_ * C_);
    float* fsb  = fcb + B_ * C_ * K_;
    float* f0b  = fsb + B_ * C_ * K_;
    float* ft   = h;      // alias: h dead when ft is written
    float* x3t  = mbuf;   // alias: m dead when x3t is zeroed

    dim3 blk(256);

    bases_kernel<<<dim3((B_ * K_ * N_) / 256), blk, 0, stream>>>(nodes, modes, node_mask, bc_t, bs_t);
    fc0_kernel<<<dim3((B_ * C_ * N_) / 256), blk, 0, stream>>>(x, fc0_w, fc0_b, h);

    for (int l = 0; l < L_; ++l) {
        hipMemsetAsync(xc, 0, sizeof(double) * (size_t)B_ * C_ * K_ * 2, stream);
        moments_kernel<<<dim3(B_, C_ / 16, 32), blk, 0, stream>>>(h, node_w, bc_t, bs_t, xc, xs);
        x0_kernel<<<dim3(B_ * C_), blk, 0, stream>>>(h, node_mask, node_w, x0);
        mix_kernel<<<dim3(B_ * C_ * K_ / 256), blk, 0, stream>>>(
            xc, xs, sp_wc + (size_t)l * C_ * C_ * K_, sp_ws + (size_t)l * C_ * C_ * K_, fcb, fsb);
        mix0_kernel<<<dim3(1), blk, 0, stream>>>(x0, sp_w0 + (size_t)l * C_ * C_, f0b);
        synth_kernel<<<dim3(B_, C_ / 8, N_ / 1024), blk, 0, stream>>>(
            h, bc_t, bs_t, node_mask, fcb, fsb, f0b, w_w + l * C_ * C_, w_b + l * C_, hnew);
        if (l != L_ - 1) {
            cgemm_kernel<true, false, false><<<dim3(B_, C_ / 16, N_ / 512), blk, 0, stream>>>(
                h, g_w1 + l * C_ * C_, g_b1 + l * C_, mbuf);
            cgemm_kernel<false, true, false><<<dim3(B_, C_ / 16, N_ / 512), blk, 0, stream>>>(
                mbuf, g_w2 + l * C_ * C_, g_b2 + l * C_, ft);
            hipMemsetAsync(x3t, 0, sizeof(float) * (size_t)B_ * C_ * N_, stream);
            scatter_kernel<<<dim3(B_ * E_ / 2), blk, 0, stream>>>(
                edges, nodes, ft, isw + l * 4, isb + l * 2, gC, l, x3t);
            combine_kernel<<<dim3(B_, C_ / 32, N_ / 64), blk, 0, stream>>>(hnew, x3t, h);
        }
    }
    // final: y1 = gelu(hnew^T @ fc1_w + b) stored (B,FC,N) into h alias; then contract with fc2
    cgemm_kernel<true, false, true><<<dim3(B_, C_ / 16, N_ / 512), blk, 0, stream>>>(
        hnew, fc1_w, fc1_b, h);
    f2_kernel<<<dim3(B_ * N_ / 256), blk, 0, stream>>>(h, fc2_w, fc2_b, out);
}

// Round 2
// 1025.957 us; speedup vs baseline: 1.2161x; 1.2161x over previous
//
#include <hip/hip_runtime.h>

constexpr int B_ = 2, N_ = 16384, E_ = 131072, C_ = 128, K_ = 64, FC_ = 128, L_ = 4;

__device__ __forceinline__ float gelu_f(float x) {
    return 0.5f * x * (1.0f + erff(x * 0.70710678118654752f));
}

// ---------------- bases: bc_t/bs_t in (B,K,N) layout, mask folded in ----------------
__global__ __launch_bounds__(256) void bases_kernel(const float* __restrict__ nodes,
                                                    const float* __restrict__ modes,
                                                    const float* __restrict__ node_mask,
                                                    float* __restrict__ bc_t,
                                                    float* __restrict__ bs_t) {
    int idx = blockIdx.x * blockDim.x + threadIdx.x;
    int n = idx & (N_ - 1);
    int k = (idx >> 14) & (K_ - 1);
    int b = idx >> 20;
    float n0 = nodes[(b * N_ + n) * 2 + 0];
    float n1 = nodes[(b * N_ + n) * 2 + 1];
    float t = n0 * modes[k * 2 + 0] + n1 * modes[k * 2 + 1];
    float s, c;
    sincosf(t, &s, &c);
    float m = node_mask[b * N_ + n];
    bc_t[idx] = c * m;
    bs_t[idx] = s * m;
}

// ---------------- fc0 ----------------
__global__ __launch_bounds__(256) void fc0_kernel(const float* __restrict__ x,
                                                  const float* __restrict__ w,
                                                  const float* __restrict__ bias,
                                                  float* __restrict__ h) {
    int idx = blockIdx.x * blockDim.x + threadIdx.x;
    int n = idx & (N_ - 1);
    int c = (idx >> 14) & (C_ - 1);
    int b = idx >> 21;
    const float* xr = x + (b * N_ + n) * 3;
    h[idx] = fmaf(xr[0], w[0 * C_ + c], fmaf(xr[1], w[1 * C_ + c], fmaf(xr[2], w[2 * C_ + c], bias[c])));
}

// ---------------- x0 moment ----------------
__global__ __launch_bounds__(256) void x0_kernel(const float* __restrict__ h,
                                                 const float* __restrict__ mask,
                                                 const float* __restrict__ wt,
                                                 double* __restrict__ x0) {
    int bc = blockIdx.x;
    int b = bc >> 7;
    int t = threadIdx.x;
    const float* hr = h + (size_t)bc * N_;
    const float* mr = mask + b * N_;
    const float* wr = wt + b * N_;
    double acc = 0.0;
    for (int n = t; n < N_; n += 256)
        acc += (double)hr[n] * (double)(mr[n] * wr[n]);
    __shared__ double red[256];
    red[t] = acc;
    __syncthreads();
    for (int s = 128; s > 0; s >>= 1) { if (t < s) red[t] += red[t + s]; __syncthreads(); }
    if (t == 0) x0[bc] = red[0];
}

// ---------------- spectral moments ----------------
__global__ __launch_bounds__(256) void moments_kernel(const float* __restrict__ h,
                                                      const float* __restrict__ wt,
                                                      const float* __restrict__ bc_t,
                                                      const float* __restrict__ bs_t,
                                                      double* __restrict__ xc,
                                                      double* __restrict__ xs) {
    int b = blockIdx.x, c0 = blockIdx.y * 16, nbase = blockIdx.z * (N_ / 32);
    __shared__ float hw[16][64];
    __shared__ float bcl[64][65];
    __shared__ float bsl[64][65];
    int t = threadIdx.x;
    int k = t & 63, cg = t >> 6;
    double ac[4] = {0, 0, 0, 0}, as[4] = {0, 0, 0, 0};
    for (int nc = 0; nc < 512; nc += 64) {
        int n0 = nbase + nc;
        __syncthreads();
        for (int i = t; i < 16 * 64; i += 256) {
            int ci = i >> 6, nj = i & 63;
            hw[ci][nj] = h[(b * C_ + c0 + ci) * N_ + n0 + nj] * wt[b * N_ + n0 + nj];
        }
        for (int i = t; i < 64 * 64; i += 256) {
            int kk = i >> 6, nj = i & 63;
            bcl[kk][nj] = bc_t[(b * K_ + kk) * N_ + n0 + nj];
            bsl[kk][nj] = bs_t[(b * K_ + kk) * N_ + n0 + nj];
        }
        __syncthreads();
        #pragma unroll 8
        for (int nj = 0; nj < 64; ++nj) {
            float bcv = bcl[k][nj], bsv = bsl[k][nj];
            #pragma unroll
            for (int r = 0; r < 4; ++r) {
                float hv = hw[cg * 4 + r][nj];
                ac[r] += (double)hv * (double)bcv;
                as[r] -= (double)hv * (double)bsv;
            }
        }
    }
    #pragma unroll
    for (int r = 0; r < 4; ++r) {
        atomicAdd(&xc[(b * C_ + c0 + cg * 4 + r) * K_ + k], ac[r]);
        atomicAdd(&xs[(b * C_ + c0 + cg * 4 + r) * K_ + k], as[r]);
    }
}

// ---------------- mode-mix, i-split 8x for parallelism ----------------
__global__ __launch_bounds__(256) void mix_kernel(const double* __restrict__ xc,
                                                  const double* __restrict__ xs,
                                                  const float* __restrict__ wc,
                                                  const float* __restrict__ ws,
                                                  double* __restrict__ mtc,
                                                  double* __restrict__ mts) {
    int idx = blockIdx.x * blockDim.x + threadIdx.x;   // (b*C + o)*K + k
    int ic = blockIdx.y;
    int k = idx & 63, o = (idx >> 6) & 127, b = idx >> 13;
    double afc = 0.0, afs = 0.0;
    for (int i = ic * 16; i < ic * 16 + 16; ++i) {
        double xcv = xc[(b * C_ + i) * K_ + k], xsv = xs[(b * C_ + i) * K_ + k];
        double wcv = (double)wc[(i * C_ + o) * K_ + k], wsv = (double)ws[(i * C_ + o) * K_ + k];
        afc += xcv * wcv - xsv * wsv;
        afs += xsv * wcv + xcv * wsv;
    }
    mtc[ic * (B_ * C_ * K_) + idx] = afc;
    mts[ic * (B_ * C_ * K_) + idx] = afs;
}

__global__ __launch_bounds__(256) void mixfin_kernel(const double* __restrict__ mtc,
                                                     const double* __restrict__ mts,
                                                     float* __restrict__ fc,
                                                     float* __restrict__ fs) {
    int idx = blockIdx.x * blockDim.x + threadIdx.x;
    double a = 0.0, s = 0.0;
    #pragma unroll
    for (int ic = 0; ic < 8; ++ic) {
        a += mtc[ic * (B_ * C_ * K_) + idx];
        s += mts[ic * (B_ * C_ * K_) + idx];
    }
    fc[idx] = (float)a;
    fs[idx] = (float)s;
}

__global__ __launch_bounds__(256) void mix0_kernel(const double* __restrict__ x0,
                                                   const float* __restrict__ w0,
                                                   float* __restrict__ f0) {
    int idx = threadIdx.x;
    int o = idx & 127, b = idx >> 7;
    double a = 0.0;
    for (int i = 0; i < C_; ++i) a += x0[b * C_ + i] * (double)w0[i * C_ + o];
    f0[idx] = (float)a;
}

// ---------------- synthesis + Conv1d fused ----------------
__global__ __launch_bounds__(256) void synth_kernel(const float* __restrict__ h,
                                                    const float* __restrict__ bc_t,
                                                    const float* __restrict__ bs_t,
                                                    const float* __restrict__ mask,
                                                    const float* __restrict__ fc,
                                                    const float* __restrict__ fs,
                                                    const float* __restrict__ f0,
                                                    const float* __restrict__ ww,
                                                    const float* __restrict__ wb,
                                                    float* __restrict__ hnew) {
    int b = blockIdx.x, o0 = blockIdx.y * 8, n0 = blockIdx.z * 1024;
    __shared__ float fc2[8][64], fs2[8][64], wwl[8][128], f0l[8], wbl[8];
    int t = threadIdx.x;
    for (int i = t; i < 8 * 64; i += 256) {
        int oi = i >> 6, kk = i & 63;
        fc2[oi][kk] = 2.0f * fc[(b * C_ + o0 + oi) * K_ + kk];
        fs2[oi][kk] = 2.0f * fs[(b * C_ + o0 + oi) * K_ + kk];
    }
    for (int i = t; i < 8 * 128; i += 256) {
        int oi = i >> 7, ii = i & 127;
        wwl[oi][ii] = ww[(o0 + oi) * C_ + ii];
    }
    if (t < 8) { f0l[t] = f0[b * C_ + o0 + t]; wbl[t] = wb[o0 + t]; }
    __syncthreads();
    int nn[4];
    float mv[4];
    #pragma unroll
    for (int j = 0; j < 4; ++j) { nn[j] = n0 + j * 256 + t; mv[j] = mask[b * N_ + nn[j]]; }
    float acc[8][4];
    #pragma unroll
    for (int oi = 0; oi < 8; ++oi)
        #pragma unroll
        for (int j = 0; j < 4; ++j) acc[oi][j] = f0l[oi] * mv[j] + wbl[oi];
    for (int kk = 0; kk < K_; ++kk) {
        const float* bcr = bc_t + (b * K_ + kk) * N_;
        const float* bsr = bs_t + (b * K_ + kk) * N_;
        float bcv[4], bsv[4];
        #pragma unroll
        for (int j = 0; j < 4; ++j) { bcv[j] = bcr[nn[j]]; bsv[j] = bsr[nn[j]]; }
        #pragma unroll
        for (int oi = 0; oi < 8; ++oi) {
            float fcv = fc2[oi][kk], fsv = fs2[oi][kk];
            #pragma unroll
            for (int j = 0; j < 4; ++j) acc[oi][j] += fcv * bcv[j] - fsv * bsv[j];
        }
    }
    for (int ii = 0; ii < C_; ++ii) {
        const float* hr = h + (b * C_ + ii) * N_;
        float hv[4];
        #pragma unroll
        for (int j = 0; j < 4; ++j) hv[j] = hr[nn[j]];
        #pragma unroll
        for (int oi = 0; oi < 8; ++oi) {
            float wv = wwl[oi][ii];
            #pragma unroll
            for (int j = 0; j < 4; ++j) acc[oi][j] += wv * hv[j];
        }
    }
    #pragma unroll
    for (int oi = 0; oi < 8; ++oi) {
        float* hw = hnew + (b * C_ + o0 + oi) * N_;
        #pragma unroll
        for (int j = 0; j < 4; ++j) hw[nn[j]] = acc[oi][j];
    }
}

// ---------------- channel GEMM: out = act(W @ in + b); 8 o x 4 n per thread ----------------
template <bool GELU_ACT, bool TRANSPOSED_OUT, bool W_TRANSPOSED>
__global__ __launch_bounds__(256) void cgemm_kernel(const float* __restrict__ in,
                                                    const float* __restrict__ W,
                                                    const float* __restrict__ bias,
                                                    float* __restrict__ out) {
    int b = blockIdx.x, o0 = blockIdx.y * 8, n0 = blockIdx.z * 1024;
    __shared__ float wl[8][128];
    __shared__ float bl[8];
    int t = threadIdx.x;
    for (int i = t; i < 8 * 128; i += 256) {
        int oi = i >> 7, ii = i & 127;
        wl[oi][ii] = W_TRANSPOSED ? W[ii * C_ + (o0 + oi)] : W[(o0 + oi) * C_ + ii];
    }
    if (t < 8) bl[t] = bias[t + o0];
    __syncthreads();
    int n = n0 + t * 4;
    float acc[8][4];
    #pragma unroll
    for (int oi = 0; oi < 8; ++oi)
        #pragma unroll
        for (int j = 0; j < 4; ++j) acc[oi][j] = bl[oi];
    for (int ii = 0; ii < C_; ++ii) {
        float4 v = *(const float4*)(in + (size_t)(b * C_ + ii) * N_ + n);
        #pragma unroll
        for (int oi = 0; oi < 8; ++oi) {
            float wv = wl[oi][ii];
            acc[oi][0] += wv * v.x;
            acc[oi][1] += wv * v.y;
            acc[oi][2] += wv * v.z;
            acc[oi][3] += wv * v.w;
        }
    }
    if (TRANSPOSED_OUT) {
        #pragma unroll
        for (int j = 0; j < 4; ++j) {
            float* orow = out + (size_t)(b * N_ + n + j) * C_ + o0;
            #pragma unroll
            for (int q = 0; q < 2; ++q) {
                float4 v4;
                v4.x = GELU_ACT ? gelu_f(acc[q * 4 + 0][j]) : acc[q * 4 + 0][j];
                v4.y = GELU_ACT ? gelu_f(acc[q * 4 + 1][j]) : acc[q * 4 + 1][j];
                v4.z = GELU_ACT ? gelu_f(acc[q * 4 + 2][j]) : acc[q * 4 + 2][j];
                v4.w = GELU_ACT ? gelu_f(acc[q * 4 + 3][j]) : acc[q * 4 + 3][j];
                *(float4*)(orow + q * 4) = v4;
            }
        }
    } else {
        #pragma unroll
        for (int oi = 0; oi < 8; ++oi) {
            float4 v4;
            v4.x = GELU_ACT ? gelu_f(acc[oi][0]) : acc[oi][0];
            v4.y = GELU_ACT ? gelu_f(acc[oi][1]) : acc[oi][1];
            v4.z = GELU_ACT ? gelu_f(acc[oi][2]) : acc[oi][2];
            v4.w = GELU_ACT ? gelu_f(acc[oi][3]) : acc[oi][3];
            *(float4*)(out + (size_t)(b * C_ + o0 + oi) * N_ + n) = v4;
        }
    }
}

// ---------------- edge binning (once per call) ----------------
__global__ __launch_bounds__(256) void hist_kernel(const int* __restrict__ edges,
                                                   int* __restrict__ cnt) {
    int be = blockIdx.x * 256 + threadIdx.x;
    int b = be >> 17;
    int tgt = edges[(size_t)be * 2 + 1];
    atomicAdd(&cnt[b * N_ + tgt], 1);
}

__global__ __launch_bounds__(256) void scanA_kernel(const int* __restrict__ cnt,
                                                    int* __restrict__ offs,
                                                    int* __restrict__ bsum) {
    __shared__ int sd[256];
    int t = threadIdx.x;
    int g = blockIdx.x * 256 + t;
    int v = cnt[g];
    sd[t] = v;
    __syncthreads();
    for (int off = 1; off < 256; off <<= 1) {
        int x = (t >= off) ? sd[t - off] : 0;
        __syncthreads();
        sd[t] += x;
        __syncthreads();
    }
    offs[g] = sd[t] - v;
    if (t == 255) bsum[blockIdx.x] = sd[255];
}

__global__ __launch_bounds__(128) void scanB_kernel(const int* __restrict__ bsum,
                                                    int* __restrict__ bbase) {
    __shared__ int sd[128];
    int t = threadIdx.x;
    int v = bsum[t];
    sd[t] = v;
    __syncthreads();
    for (int off = 1; off < 128; off <<= 1) {
        int x = (t >= off) ? sd[t - off] : 0;
        __syncthreads();
        sd[t] += x;
        __syncthreads();
    }
    bbase[t] = sd[t] - v;
}

__global__ __launch_bounds__(256) void scanC_kernel(int* __restrict__ offs,
                                                    const int* __restrict__ bbase) {
    int t = threadIdx.x;
    int g = blockIdx.x * 256 + t;
    offs[g] += bbase[blockIdx.x];
    if (g == 0) offs[B_ * N_] = B_ * E_;
}

__global__ __launch_bounds__(256) void fill_kernel(const int* __restrict__ edges,
                                                   const float* __restrict__ nodes,
                                                   const int* __restrict__ offs,
                                                   int* __restrict__ cursor,
                                                   int* __restrict__ ssrc,
                                                   float2* __restrict__ sef) {
    int be = blockIdx.x * 256 + threadIdx.x;
    int b = be >> 17;
    int src = edges[(size_t)be * 2 + 0];
    int tgt = edges[(size_t)be * 2 + 1];
    int bin = b * N_ + tgt;
    int pos = atomicAdd(&cursor[bin], 1);
    int idx = offs[bin] + pos;
    ssrc[idx] = b * N_ + src;
    float2 ef;
    ef.x = nodes[(size_t)(b * N_ + src) * 2 + 0] - nodes[(size_t)(b * N_ + tgt) * 2 + 0];
    ef.y = nodes[(size_t)(b * N_ + src) * 2 + 1] - nodes[(size_t)(b * N_ + tgt) * 2 + 1];
    sef[idx] = ef;
}

// ---------------- per-layer edge kernel values ----------------
__global__ __launch_bounds__(256) void ker_kernel(const float2* __restrict__ sef,
                                                  const float* __restrict__ isw,
                                                  const float* __restrict__ isb,
                                                  const float* __restrict__ gC,
                                                  int l,
                                                  float* __restrict__ kerb) {
    int m = blockIdx.x * 256 + threadIdx.x;
    float2 ef = sef[m];
    float sig0 = isw[0] * ef.x + isw[1] * ef.y + isb[0];
    float sig1 = isw[2] * ef.x + isw[3] * ef.y + isb[1];
    kerb[m] = gC[l] * expf(ef.x * sig0 + ef.y * sig1);
}

// ---------------- per-target gather (replaces atomic scatter) ----------------
__global__ __launch_bounds__(256) void gather_kernel(const int* __restrict__ offs,
                                                     const int* __restrict__ ssrc,
                                                     const float* __restrict__ kerb,
                                                     const float* __restrict__ ft,
                                                     float* __restrict__ x3t) {
    int t = threadIdx.x;
    int row = blockIdx.x * 2 + (t >> 7);   // b*N + n
    int c = t & 127;
    int start = offs[row], end = offs[row + 1];
    float acc = 0.0f;
    for (int j = start; j < end; ++j) {
        int s = ssrc[j];
        float kv = kerb[j];
        acc += ft[(size_t)s * C_ + c] * kv;
    }
    x3t[(size_t)row * C_ + c] = acc;
}

// ---------------- combine: h = gelu(hnew) + gelu(x3t^T) ----------------
__global__ __launch_bounds__(256) void combine_kernel(const float* __restrict__ hnew,
                                                      const float* __restrict__ x3t,
                                                      float* __restrict__ h) {
    int b = blockIdx.x, c0 = blockIdx.y * 32, n0 = blockIdx.z * 64;
    __shared__ float tl[32][65];
    int t = threadIdx.x;
    int ci = t & 31, nj = t >> 5;
    #pragma unroll
    for (int p = 0; p < 8; ++p) {
        int n = n0 + p * 8 + nj;
        tl[ci][p * 8 + nj] = x3t[(size_t)(b * N_ + n) * C_ + c0 + ci];
    }
    __syncthreads();
    int nj2 = t & 63, ci2 = t >> 6;
    #pragma unroll
    for (int p = 0; p < 8; ++p) {
        int c = c0 + p * 4 + ci2;
        int idx = (b * C_ + c) * N_ + n0 + nj2;
        h[idx] = gelu_f(hnew[idx]) + gelu_f(tl[p * 4 + ci2][nj2]);
    }
}

// ---------------- final fc2 contraction ----------------
__global__ __launch_bounds__(256) void f2_kernel(const float* __restrict__ y1,
                                                 const float* __restrict__ w2,
                                                 const float* __restrict__ b2,
                                                 float* __restrict__ out) {
    int idx = blockIdx.x * blockDim.x + threadIdx.x;
    int n = idx & (N_ - 1), b = idx >> 14;
    float acc = b2[0];
    for (int f = 0; f < FC_; ++f) acc += y1[(b * FC_ + f) * N_ + n] * w2[f];
    out[idx] = acc;
}

extern "C" void kernel_launch(void* const* d_in, const int* in_sizes, int n_in,
                              void* d_out, int out_size, void* d_ws, size_t ws_size,
                              hipStream_t stream) {
    const float* x         = (const float*)d_in[0];
    const float* node_mask = (const float*)d_in[1];
    const float* nodes     = (const float*)d_in[2];
    const float* node_w    = (const float*)d_in[3];
    const int*   edges     = (const int*)d_in[4];
    const float* modes     = (const float*)d_in[5];
    const float* fc0_w     = (const float*)d_in[6];
    const float* fc0_b     = (const float*)d_in[7];
    const float* sp_wc     = (const float*)d_in[8];
    const float* sp_ws     = (const float*)d_in[9];
    const float* sp_w0     = (const float*)d_in[10];
    const float* w_w       = (const float*)d_in[11];
    const float* w_b       = (const float*)d_in[12];
    const float* g_w1      = (const float*)d_in[13];
    const float* g_b1      = (const float*)d_in[14];
    const float* g_w2      = (const float*)d_in[15];
    const float* g_b2      = (const float*)d_in[16];
    const float* isw       = (const float*)d_in[17];
    const float* isb       = (const float*)d_in[18];
    const float* gC        = (const float*)d_in[19];
    const float* fc1_w     = (const float*)d_in[20];
    const float* fc1_b     = (const float*)d_in[21];
    const float* fc2_w     = (const float*)d_in[22];
    const float* fc2_b     = (const float*)d_in[23];
    float* out = (float*)d_out;

    // ---- workspace layout ----
    float* bc_t = (float*)d_ws;                          // 2M floats
    float* bs_t = bc_t + (size_t)B_ * K_ * N_;           // 2M
    float* h    = bs_t + (size_t)B_ * K_ * N_;           // 4M
    float* hnew = h + (size_t)B_ * C_ * N_;              // 4M
    float* mbuf = hnew + (size_t)B_ * C_ * N_;           // 4M
    double* xc  = (double*)(mbuf + (size_t)B_ * C_ * N_);
    double* xs  = xc + B_ * C_ * K_;
    double* x0  = xs + B_ * C_ * K_;                     // 256
    double* mtc = x0 + 256;                              // 8*16384
    double* mts = mtc + 8 * B_ * C_ * K_;
    float2* sef = (float2*)(mts + 8 * B_ * C_ * K_);     // B*E float2
    float* fcb  = (float*)(sef + (size_t)B_ * E_);
    float* fsb  = fcb + B_ * C_ * K_;
    float* f0b  = fsb + B_ * C_ * K_;                    // 256
    float* kerb = f0b + 256;                             // B*E
    int* offs   = (int*)(kerb + (size_t)B_ * E_);        // B*N+1 (+pad)
    int* cnt    = offs + B_ * N_ + 4;
    int* cursor = cnt + B_ * N_;
    int* bsum   = cursor + B_ * N_;                      // 128
    int* bbase  = bsum + 128;                            // 128
    int* ssrc   = bbase + 128;                           // B*E
    float* ft   = h;      // alias: h dead when ft is written
    float* x3t  = mbuf;   // alias: mbuf dead when x3t written

    dim3 blk(256);

    bases_kernel<<<dim3((B_ * K_ * N_) / 256), blk, 0, stream>>>(nodes, modes, node_mask, bc_t, bs_t);
    fc0_kernel<<<dim3((B_ * C_ * N_) / 256), blk, 0, stream>>>(x, fc0_w, fc0_b, h);

    // ---- edge binning (once) ----
    hipMemsetAsync(cnt, 0, sizeof(int) * B_ * N_, stream);
    hist_kernel<<<dim3(B_ * E_ / 256), blk, 0, stream>>>(edges, cnt);
    scanA_kernel<<<dim3(B_ * N_ / 256), blk, 0, stream>>>(cnt, offs, bsum);
    scanB_kernel<<<dim3(1), dim3(128), 0, stream>>>(bsum, bbase);
    scanC_kernel<<<dim3(B_ * N_ / 256), blk, 0, stream>>>(offs, bbase);
    hipMemsetAsync(cursor, 0, sizeof(int) * B_ * N_, stream);
    fill_kernel<<<dim3(B_ * E_ / 256), blk, 0, stream>>>(edges, nodes, offs, cursor, ssrc, sef);

    for (int l = 0; l < L_; ++l) {
        hipMemsetAsync(xc, 0, sizeof(double) * (size_t)B_ * C_ * K_ * 2, stream);
        moments_kernel<<<dim3(B_, C_ / 16, 32), blk, 0, stream>>>(h, node_w, bc_t, bs_t, xc, xs);
        x0_kernel<<<dim3(B_ * C_), blk, 0, stream>>>(h, node_mask, node_w, x0);
        mix_kernel<<<dim3(B_ * C_ * K_ / 256, 8), blk, 0, stream>>>(
            xc, xs, sp_wc + (size_t)l * C_ * C_ * K_, sp_ws + (size_t)l * C_ * C_ * K_, mtc, mts);
        mixfin_kernel<<<dim3(B_ * C_ * K_ / 256), blk, 0, stream>>>(mtc, mts, fcb, fsb);
        mix0_kernel<<<dim3(1), blk, 0, stream>>>(x0, sp_w0 + (size_t)l * C_ * C_, f0b);
        synth_kernel<<<dim3(B_, C_ / 8, N_ / 1024), blk, 0, stream>>>(
            h, bc_t, bs_t, node_mask, fcb, fsb, f0b, w_w + l * C_ * C_, w_b + l * C_, hnew);
        if (l != L_ - 1) {
            cgemm_kernel<true, false, false><<<dim3(B_, C_ / 8, N_ / 1024), blk, 0, stream>>>(
                h, g_w1 + l * C_ * C_, g_b1 + l * C_, mbuf);
            cgemm_kernel<false, true, false><<<dim3(B_, C_ / 8, N_ / 1024), blk, 0, stream>>>(
                mbuf, g_w2 + l * C_ * C_, g_b2 + l * C_, ft);
            ker_kernel<<<dim3(B_ * E_ / 256), blk, 0, stream>>>(sef, isw + l * 4, isb + l * 2, gC, l, kerb);
            gather_kernel<<<dim3(B_ * N_ / 2), blk, 0, stream>>>(offs, ssrc, kerb, ft, x3t);
            combine_kernel<<<dim3(B_, C_ / 32, N_ / 64), blk, 0, stream>>>(hnew, x3t, h);
        }
    }
    cgemm_kernel<true, false, true><<<dim3(B_, C_ / 8, N_ / 1024), blk, 0, stream>>>(
        hnew, fc1_w, fc1_b, h);
    f2_kernel<<<dim3(B_ * N_ / 256), blk, 0, stream>>>(h, fc2_w, fc2_b, out);
}